// Round 10
// baseline (381.592 us; speedup 1.0000x reference)
//
#include <hip/hip_runtime.h>
#include <math.h>

#define BB 32768
#define DD 512
#define CC 527
#define NCOLP 576   // padded W cols (36 tiles of 16)
#define ZLD 528     // z row stride (floats)
#define BM 32       // rows per gemm block (2 row-groups x 16)

typedef __attribute__((ext_vector_type(8))) short bf16x8;
typedef __attribute__((ext_vector_type(4))) short bf16x4;
typedef __attribute__((ext_vector_type(4))) float f32x4;

// Named-SSA accumulators (R6 lesson: f32x4 arrays never promote -> scratch).
#define FJ(OP) OP(0) OP(1) OP(2) OP(3) OP(4) OP(5) OP(6) OP(7) OP(8)
#define FRJ_R(OP, r) OP(r,0) OP(r,1) OP(r,2) OP(r,3) OP(r,4) OP(r,5) OP(r,6) OP(r,7) OP(r,8)
#define FRJ(OP) FRJ_R(OP,0) FRJ_R(OP,1) FRJ_R(OP,2) FRJ_R(OP,3)

#if __has_builtin(__builtin_amdgcn_exp2f)
#define EXP2F(v) __builtin_amdgcn_exp2f(v)
#else
#define EXP2F(v) exp2f(v)
#endif
#if __has_builtin(__builtin_amdgcn_logf)
#define LOG2F(v) __builtin_amdgcn_logf(v)
#else
#define LOG2F(v) __log2f(v)
#endif

__device__ __forceinline__ short f2bf(float f) {  // fp32 -> bf16 RNE
  unsigned u = __float_as_uint(f);
  u += 0x7fffu + ((u >> 16) & 1u);
  return (short)(u >> 16);
}
__device__ __forceinline__ bf16x8 pack8(f32x4 a, f32x4 b) {
  bf16x8 v;
  v[0]=f2bf(a.x); v[1]=f2bf(a.y); v[2]=f2bf(a.z); v[3]=f2bf(a.w);
  v[4]=f2bf(b.x); v[5]=f2bf(b.y); v[6]=f2bf(b.z); v[7]=f2bf(b.w);
  return v;
}

// ============ Kernel 1: pure GEMM, z = x@W^T + b -> global ============
// 512 thr = 8 waves = 2 row-groups x 4 col-groups; wave = 16 rows x 9
// interleaved col-tiles (36 acc regs). Barrier-free; B streams from L2;
// x prefetched 3 k-steps deep (~525 cy cover vs R9's 1-step ~175 cy).
__global__ __launch_bounds__(512, 4)
void gemm_z(const float* __restrict__ x, const short* __restrict__ Wbf,
            const float* __restrict__ bias, float* __restrict__ z) {
  const int tid  = threadIdx.x;
  const int w    = tid >> 6, lane = tid & 63;
  const int cl   = lane & 15, quad = lane >> 4;
  const int rg   = w >> 2, cg = w & 3;
  const int row0 = blockIdx.x * BM;

#define DECL(j) f32x4 A##j = (f32x4){0.f, 0.f, 0.f, 0.f};
  FJ(DECL)
#undef DECL

  const float* ax = x + (size_t)(row0 + rg * 16 + cl) * DD + quad * 8;
  f32x4 p0a = *(const f32x4*)(ax);      f32x4 p0b = *(const f32x4*)(ax + 4);
  f32x4 p1a = *(const f32x4*)(ax + 32); f32x4 p1b = *(const f32x4*)(ax + 36);
  f32x4 p2a = *(const f32x4*)(ax + 64); f32x4 p2b = *(const f32x4*)(ax + 68);

#pragma unroll
  for (int k0 = 0; k0 < DD; k0 += 32) {
    bf16x8 af = pack8(p0a, p0b);
    p0a = p1a; p0b = p1b; p1a = p2a; p1b = p2b;
    if (k0 + 96 < DD) {
      p2a = *(const f32x4*)(ax + k0 + 96);
      p2b = *(const f32x4*)(ax + k0 + 100);
    }
#define MFS(j) { \
    bf16x8 bfr = *(const bf16x8*)(Wbf + (size_t)((cg + 4*(j)) * 16 + cl) * DD + k0 + quad * 8); \
    A##j = __builtin_amdgcn_mfma_f32_16x16x32_bf16(af, bfr, A##j, 0, 0, 0); }
    FJ(MFS)
#undef MFS
  }

  // store z (+bias). C/D: col=(cg+4j)*16+cl, local row = rg*16+quad*4+r
  const size_t rb = (size_t)(row0 + rg * 16 + quad * 4);
#define WRZ(j) { \
    int col = (cg + 4*(j)) * 16 + cl; \
    if (col < ZLD) { \
      float bt = (col < CC) ? bias[col] : 0.f; \
      z[(rb + 0) * ZLD + col] = A##j[0] + bt; \
      z[(rb + 1) * ZLD + col] = A##j[1] + bt; \
      z[(rb + 2) * ZLD + col] = A##j[2] + bt; \
      z[(rb + 3) * ZLD + col] = A##j[3] + bt; \
    } }
  FJ(WRZ)
#undef WRZ
}

// ============ Kernel 2: epilogue — loss + per-row top-k score ============
// 256 thr = 4 waves; each wave owns 4 whole rows (16 rows/block).
// Coalesced z/y reads; in-wave bisection (no barriers, early exit).
__global__ __launch_bounds__(256, 4)
void epi_topk(const float* __restrict__ z, const float* __restrict__ y,
              const float* __restrict__ pw, float* __restrict__ accum) {
  __shared__ float redL[4], redS[4];
  const int tid  = threadIdx.x;
  const int w    = tid >> 6, lane = tid & 63;
  const size_t grow = (size_t)blockIdx.x * 16 + w * 4;

#define LDP(j) float pv##j = ((lane + 64*(j)) < CC) ? pw[lane + 64*(j)] : 1.f;
  FJ(LDP)
#undef LDP

#define DZ(r,j) float Z##r##_##j = -1e30f;
  FRJ(DZ)
#undef DZ
  unsigned ym0 = 0, ym1 = 0, ym2 = 0, ym3 = 0;
  float lossloc = 0.f;

#define EPI(r,j) { \
    int col = lane + 64*(j); \
    if (col < CC) { \
      float zv = z[(grow + (r)) * ZLD + col]; \
      Z##r##_##j = zv; \
      float yv = __builtin_nontemporal_load(&y[(grow + (r)) * CC + col]); \
      float l1 = LOG2F(1.f + EXP2F(fabsf(zv) * -1.4426950408889634f)) * 0.6931471805599453f; \
      float sp = fmaxf(zv, 0.f) + l1; \
      lossloc += pv##j * yv * (sp - zv) + (1.f - yv) * sp; \
      if (yv > 0.5f) ym##r |= (1u << (j)); \
    } }
  FRJ(EPI)
#undef EPI

  unsigned kp01 = (unsigned)__popc(ym0) | ((unsigned)__popc(ym1) << 16);
  unsigned kp23 = (unsigned)__popc(ym2) | ((unsigned)__popc(ym3) << 16);
#pragma unroll
  for (int m = 1; m < 64; m <<= 1) {
    kp01 += __shfl_xor(kp01, m, 64);
    kp23 += __shfl_xor(kp23, m, 64);
  }
  const int kr[4] = {(int)(kp01 & 0xffffu), (int)(kp01 >> 16),
                     (int)(kp23 & 0xffffu), (int)(kp23 >> 16)};

  float lo[4], hi[4], th[4];
  bool fnd[4];
#pragma unroll
  for (int r = 0; r < 4; ++r) { lo[r] = -16.f; hi[r] = 16.f; th[r] = 0.f; fnd[r] = false; }

#pragma unroll 1
  for (int it = 0; it < 30; ++it) {
    float tm[4];
#pragma unroll
    for (int r = 0; r < 4; ++r) tm[r] = 0.5f * (lo[r] + hi[r]);
    int c[4] = {0, 0, 0, 0};
#define CNT(r,j) c[r] += (Z##r##_##j > tm[r]) ? 1 : 0;
    FRJ(CNT)
#undef CNT
    unsigned p01 = (unsigned)c[0] | ((unsigned)c[1] << 16);
    unsigned p23 = (unsigned)c[2] | ((unsigned)c[3] << 16);
#pragma unroll
    for (int m = 1; m < 64; m <<= 1) {
      p01 += __shfl_xor(p01, m, 64);
      p23 += __shfl_xor(p23, m, 64);
    }
    const int tot[4] = {(int)(p01 & 0xffffu), (int)(p01 >> 16),
                        (int)(p23 & 0xffffu), (int)(p23 >> 16)};
#pragma unroll
    for (int r = 0; r < 4; ++r) {
      if (!fnd[r]) {
        if (tot[r] == kr[r])                       { th[r] = tm[r]; fnd[r] = true; }
        else if (tm[r] <= lo[r] || tm[r] >= hi[r]) { th[r] = lo[r]; fnd[r] = true; }
        else if (tot[r] > kr[r])                   lo[r] = tm[r];
        else                                       hi[r] = tm[r];
      }
    }
    if (fnd[0] && fnd[1] && fnd[2] && fnd[3]) break;  // wave-uniform
  }
#pragma unroll
  for (int r = 0; r < 4; ++r) if (!fnd[r]) th[r] = lo[r];

  int h[4] = {0, 0, 0, 0};
#define HIT(r,j) if (((ym##r >> (j)) & 1u) && Z##r##_##j > th[r]) h[r]++;
  FRJ(HIT)
#undef HIT
  unsigned q01 = (unsigned)h[0] | ((unsigned)h[1] << 16);
  unsigned q23 = (unsigned)h[2] | ((unsigned)h[3] << 16);
#pragma unroll
  for (int m = 1; m < 64; m <<= 1) {
    q01 += __shfl_xor(q01, m, 64);
    q23 += __shfl_xor(q23, m, 64);
  }
  float scoreloc = 0.f;
  if (lane == 0) {
    const int hh[4] = {(int)(q01 & 0xffffu), (int)(q01 >> 16),
                       (int)(q23 & 0xffffu), (int)(q23 >> 16)};
#pragma unroll
    for (int r = 0; r < 4; ++r) {
      int hv = hh[r] < kr[r] ? hh[r] : kr[r];
      scoreloc += (float)hv / (float)kr[r];
    }
  }

#pragma unroll
  for (int m = 1; m < 64; m <<= 1) lossloc += __shfl_xor(lossloc, m, 64);
  if (lane == 0) { redL[w] = lossloc; redS[w] = scoreloc; }
  __syncthreads();
  if (tid == 0) {
    atomicAdd(&accum[0], redL[0] + redL[1] + redL[2] + redL[3]);
    atomicAdd(&accum[1], redS[0] + redS[1] + redS[2] + redS[3]);
  }
}

// ============ Fused fallback (R9, 238us) for small ws ============
template<bool PRE>
__global__ __launch_bounds__(512, 4)
void fused_mfma_bce_topk(const float* __restrict__ x, const float* __restrict__ y,
                         const float* __restrict__ W, const short* __restrict__ Wbf,
                         const float* __restrict__ bias, const float* __restrict__ pw,
                         float* __restrict__ accum) {
  __shared__ float zs[BM][532];
  __shared__ float redL[8], redS[8];
  const int tid  = threadIdx.x;
  const int w    = tid >> 6, lane = tid & 63;
  const int cl   = lane & 15, quad = lane >> 4;
  const int rg   = w >> 2, cg = w & 3;
  const int row0 = blockIdx.x * BM;

#define DECL(j) f32x4 A##j = (f32x4){0.f, 0.f, 0.f, 0.f};
  FJ(DECL)
#undef DECL
  const float* ax = x + (size_t)(row0 + rg * 16 + cl) * DD + quad * 8;
  f32x4 pa0 = *(const f32x4*)(ax);
  f32x4 pa1 = *(const f32x4*)(ax + 4);
  for (int k0 = 0; k0 < DD; k0 += 32) {
    bf16x8 af = pack8(pa0, pa1);
    if (k0 + 32 < DD) { pa0 = *(const f32x4*)(ax + k0 + 32); pa1 = *(const f32x4*)(ax + k0 + 36); }
    if (PRE) {
#define MFS(j) { \
      bf16x8 bfr = *(const bf16x8*)(Wbf + (size_t)((cg + 4*(j)) * 16 + cl) * DD + k0 + quad * 8); \
      A##j = __builtin_amdgcn_mfma_f32_16x16x32_bf16(af, bfr, A##j, 0, 0, 0); }
      FJ(MFS)
#undef MFS
    } else {
#define MFSF(j) { \
      int col = (cg + 4*(j)) * 16 + cl; \
      bf16x8 bfr = {0,0,0,0,0,0,0,0}; \
      if (col < CC) { \
        const float* wp = W + (size_t)col * DD + k0 + quad * 8; \
        bfr = pack8(*(const f32x4*)wp, *(const f32x4*)(wp + 4)); \
      } \
      A##j = __builtin_amdgcn_mfma_f32_16x16x32_bf16(af, bfr, A##j, 0, 0, 0); }
      FJ(MFSF)
#undef MFSF
    }
  }
#define WRZ(j) { \
    int col = (cg + 4*(j)) * 16 + cl; \
    if (col < 528) { \
      float bt = (col < CC) ? bias[col] : 0.f; \
      int rr0 = rg * 16 + quad * 4; \
      zs[rr0 + 0][col] = A##j[0] + bt; \
      zs[rr0 + 1][col] = A##j[1] + bt; \
      zs[rr0 + 2][col] = A##j[2] + bt; \
      zs[rr0 + 3][col] = A##j[3] + bt; \
    } }
  FJ(WRZ)
#undef WRZ
  __syncthreads();
  const int lrow = w * 4;
  const size_t grow = (size_t)(row0 + lrow);
#define LDP(j) float pv##j = ((lane + 64*(j)) < CC) ? pw[lane + 64*(j)] : 1.f;
  FJ(LDP)
#undef LDP
#define DZ(r,j) float Z##r##_##j = -1e30f;
  FRJ(DZ)
#undef DZ
  unsigned ym0 = 0, ym1 = 0, ym2 = 0, ym3 = 0;
  float lossloc = 0.f;
#define EPI(r,j) { \
    int col = lane + 64*(j); \
    if (col < CC) { \
      float zv = zs[lrow + (r)][col]; \
      Z##r##_##j = zv; \
      float yv = __builtin_nontemporal_load(&y[(grow + (r)) * CC + col]); \
      float l1 = LOG2F(1.f + EXP2F(fabsf(zv) * -1.4426950408889634f)) * 0.6931471805599453f; \
      float sp = fmaxf(zv, 0.f) + l1; \
      lossloc += pv##j * yv * (sp - zv) + (1.f - yv) * sp; \
      if (yv > 0.5f) ym##r |= (1u << (j)); \
    } }
  FRJ(EPI)
#undef EPI
  unsigned kp01 = (unsigned)__popc(ym0) | ((unsigned)__popc(ym1) << 16);
  unsigned kp23 = (unsigned)__popc(ym2) | ((unsigned)__popc(ym3) << 16);
#pragma unroll
  for (int m = 1; m < 64; m <<= 1) { kp01 += __shfl_xor(kp01, m, 64); kp23 += __shfl_xor(kp23, m, 64); }
  const int kr[4] = {(int)(kp01 & 0xffffu), (int)(kp01 >> 16),
                     (int)(kp23 & 0xffffu), (int)(kp23 >> 16)};
  float lo[4], hi[4], th[4]; bool fnd[4];
#pragma unroll
  for (int r = 0; r < 4; ++r) { lo[r] = -16.f; hi[r] = 16.f; th[r] = 0.f; fnd[r] = false; }
#pragma unroll 1
  for (int it = 0; it < 30; ++it) {
    float tm[4];
#pragma unroll
    for (int r = 0; r < 4; ++r) tm[r] = 0.5f * (lo[r] + hi[r]);
    int c[4] = {0, 0, 0, 0};
#define CNT(r,j) c[r] += (Z##r##_##j > tm[r]) ? 1 : 0;
    FRJ(CNT)
#undef CNT
    unsigned p01 = (unsigned)c[0] | ((unsigned)c[1] << 16);
    unsigned p23 = (unsigned)c[2] | ((unsigned)c[3] << 16);
#pragma unroll
    for (int m = 1; m < 64; m <<= 1) { p01 += __shfl_xor(p01, m, 64); p23 += __shfl_xor(p23, m, 64); }
    const int tot[4] = {(int)(p01 & 0xffffu), (int)(p01 >> 16),
                        (int)(p23 & 0xffffu), (int)(p23 >> 16)};
#pragma unroll
    for (int r = 0; r < 4; ++r) {
      if (!fnd[r]) {
        if (tot[r] == kr[r])                       { th[r] = tm[r]; fnd[r] = true; }
        else if (tm[r] <= lo[r] || tm[r] >= hi[r]) { th[r] = lo[r]; fnd[r] = true; }
        else if (tot[r] > kr[r])                   lo[r] = tm[r];
        else                                       hi[r] = tm[r];
      }
    }
    if (fnd[0] && fnd[1] && fnd[2] && fnd[3]) break;
  }
#pragma unroll
  for (int r = 0; r < 4; ++r) if (!fnd[r]) th[r] = lo[r];
  int h[4] = {0, 0, 0, 0};
#define HIT(r,j) if (((ym##r >> (j)) & 1u) && Z##r##_##j > th[r]) h[r]++;
  FRJ(HIT)
#undef HIT
  unsigned q01 = (unsigned)h[0] | ((unsigned)h[1] << 16);
  unsigned q23 = (unsigned)h[2] | ((unsigned)h[3] << 16);
#pragma unroll
  for (int m = 1; m < 64; m <<= 1) { q01 += __shfl_xor(q01, m, 64); q23 += __shfl_xor(q23, m, 64); }
  float scoreloc = 0.f;
  if (lane == 0) {
    const int hh[4] = {(int)(q01 & 0xffffu), (int)(q01 >> 16),
                       (int)(q23 & 0xffffu), (int)(q23 >> 16)};
#pragma unroll
    for (int r = 0; r < 4; ++r) {
      int hv = hh[r] < kr[r] ? hh[r] : kr[r];
      scoreloc += (float)hv / (float)kr[r];
    }
  }
#pragma unroll
  for (int m = 1; m < 64; m <<= 1) lossloc += __shfl_xor(lossloc, m, 64);
  if (lane == 0) { redL[w] = lossloc; redS[w] = scoreloc; }
  __syncthreads();
  if (tid == 0) {
    float sl = 0.f, ss = 0.f;
#pragma unroll
    for (int i = 0; i < 8; ++i) { sl += redL[i]; ss += redS[i]; }
    atomicAdd(&accum[0], sl);
    atomicAdd(&accum[1], ss);
  }
}

__global__ void wcvt_kernel(const float* __restrict__ W, short* __restrict__ Wbf,
                            float* __restrict__ ws) {
  if (blockIdx.x == 0 && threadIdx.x == 0) { ws[0] = 0.f; ws[1] = 0.f; }
  int idx = (blockIdx.x * 256 + threadIdx.x) * 4;
  int row = idx >> 9;
  bf16x4 v = {0, 0, 0, 0};
  if (row < CC) {
    f32x4 f = *(const f32x4*)(W + idx);
    v[0]=f2bf(f.x); v[1]=f2bf(f.y); v[2]=f2bf(f.z); v[3]=f2bf(f.w);
  }
  *(bf16x4*)(Wbf + idx) = v;
}

__global__ void init_ws_kernel(float* ws) { ws[0] = 0.f; ws[1] = 0.f; }

__global__ void finalize_kernel(const float* __restrict__ ws, float* __restrict__ out) {
  out[0] = (float)((double)ws[0] / ((double)BB * (double)CC));
  out[1] = (float)((double)ws[1] / (double)BB);
}

extern "C" void kernel_launch(void* const* d_in, const int* in_sizes, int n_in,
                              void* d_out, int out_size, void* d_ws, size_t ws_size,
                              hipStream_t stream) {
  const float* x  = (const float*)d_in[0];
  const float* y  = (const float*)d_in[1];
  const float* W  = (const float*)d_in[2];
  const float* b  = (const float*)d_in[3];
  const float* pw = (const float*)d_in[4];
  float* out = (float*)d_out;
  float* ws  = (float*)d_ws;
  short* Wbf = (short*)((char*)d_ws + 64);
  float* z   = (float*)((char*)d_ws + 64 + (size_t)NCOLP * DD * 2);  // 16B-aligned

  const size_t need_pre   = 64 + (size_t)NCOLP * DD * 2;
  const size_t need_split = need_pre + (size_t)BB * ZLD * 4;

  if (ws_size >= need_split) {
    wcvt_kernel<<<dim3(NCOLP * DD / 1024), dim3(256), 0, stream>>>(W, Wbf, ws);
    gemm_z<<<dim3(BB / BM), dim3(512), 0, stream>>>(x, Wbf, b, z);
    epi_topk<<<dim3(BB / 16), dim3(256), 0, stream>>>(z, y, pw, ws);
  } else if (ws_size >= need_pre) {
    wcvt_kernel<<<dim3(NCOLP * DD / 1024), dim3(256), 0, stream>>>(W, Wbf, ws);
    fused_mfma_bce_topk<true><<<dim3(BB / BM), dim3(512), 0, stream>>>(
        x, y, W, Wbf, b, pw, ws);
  } else {
    init_ws_kernel<<<dim3(1), dim3(1), 0, stream>>>(ws);
    fused_mfma_bce_topk<false><<<dim3(BB / BM), dim3(512), 0, stream>>>(
        x, y, W, Wbf, b, pw, ws);
  }
  finalize_kernel<<<dim3(1), dim3(1), 0, stream>>>(ws, out);
}